// Round 1
// baseline (306.437 us; speedup 1.0000x reference)
//
#include <hip/hip_runtime.h>
#include <hip/hip_bf16.h>
#include <stdint.h>

typedef __bf16 bf16_t;
typedef bf16_t bf16x8 __attribute__((ext_vector_type(8)));
typedef float f32x4 __attribute__((ext_vector_type(4)));

#define NB 128
#define BS 64
#define KSZ 16
#define T_LEN 2048
#define C_LEN 2048
#define NBR 32
#define TN 512

// ---------------------------------------------------------------------------
// Prepack weights into per-lane MFMA A-fragment layout (bf16):
// wpk[blk][ks(32)][mt(4)][lane(64)][j(8)]
//   = bv[blk][o = mt*16 + (lane&15)][i = (ks&1)*32 + (lane>>4)*8 + j][k = ks>>1]
// K-order: kk = k*64 + i  (K-step of 32 = fixed k, half of the i range)
// ---------------------------------------------------------------------------
__global__ __launch_bounds__(256) void prepack_kernel(
    const float* __restrict__ bv, bf16_t* __restrict__ wpk)
{
  const int blk = blockIdx.x;
  const int mt  = blockIdx.y;
  const int tid = threadIdx.x;
  __shared__ float lw[16 * 64 * 17];   // [o_local][i][k], k padded 16->17

  const float* src = bv + (size_t)blk * 65536 + (size_t)mt * 16384;
  for (int p = 0; p < 16; ++p) {
    int idx = p * 1024 + tid * 4;              // = o*1024 + i*16 + k
    const float4 v = *(const float4*)(src + idx);
    int o = idx >> 10;
    int i = (idx >> 4) & 63;
    int k = idx & 15;                          // in {0,4,8,12}
    float* d = &lw[(o * 64 + i) * 17 + k];
    d[0] = v.x; d[1] = v.y; d[2] = v.z; d[3] = v.w;
  }
  __syncthreads();

  const int e0 = tid * 2;        // element pair within [lane][j] (512 per ks)
  const int l  = e0 >> 3;
  const int j  = e0 & 7;         // even
  const int o  = l & 15;
  for (int ks = 0; ks < 32; ++ks) {
    const int k  = ks >> 1;
    const int i0 = (ks & 1) * 32 + (l >> 4) * 8 + j;
    const float a = lw[(o * 64 + i0) * 17 + k];
    const float b = lw[(o * 64 + i0 + 1) * 17 + k];
    const uint16_t ba = __builtin_bit_cast(uint16_t, (bf16_t)a);
    const uint16_t bb = __builtin_bit_cast(uint16_t, (bf16_t)b);
    const uint32_t packed = (uint32_t)ba | ((uint32_t)bb << 16);
    const size_t off = ((((size_t)blk * 32 + ks) * 4 + mt) * 512) + e0;
    *(uint32_t*)(wpk + off) = packed;
  }
}

// ---------------------------------------------------------------------------
// Main kernel: one WG per (t-tile, target block-row, batch).
// Accumulates all blocks with rows[blk]==tr in registers, stores once.
// 4 waves; wave wv owns t-columns [wv*128, wv*128+128) of the 512-wide tile.
// Per wave: 4 M-tiles x 8 N-tiles of 16x16 accumulators.
// ---------------------------------------------------------------------------
__global__ __launch_bounds__(256, 1) void bsconv_kernel(
    const float* __restrict__ x, const bf16_t* __restrict__ wpk,
    const int* __restrict__ cols, const int* __restrict__ rows,
    float* __restrict__ y)
{
  const int tt = blockIdx.x;        // 0..3
  const int tr = blockIdx.y;        // 0..31
  const int n  = blockIdx.z;        // 0..3
  const int t0 = tt * TN;
  const int tid  = threadIdx.x;
  const int lane = tid & 63;
  const int wv   = tid >> 6;

  // xst[u][i]: u in [0,528) = t0-15+u along time, i in [0,64) along channel.
  // Row stride 72 bf16 = 144 B (16B-aligned rows; uniform 8-access/bank reads).
  __shared__ __attribute__((aligned(16))) bf16_t xst[528 * 72];
  __shared__ __attribute__((aligned(16))) bf16_t wlds[2][16384];  // 2 x 32 KB

  f32x4 acc[4][8];
  #pragma unroll
  for (int a = 0; a < 4; ++a)
    #pragma unroll
    for (int b = 0; b < 8; ++b) {
      f32x4 z = {0.f, 0.f, 0.f, 0.f};
      acc[a][b] = z;
    }

  for (int blk = 0; blk < NB; ++blk) {
    if (rows[blk] != tr) continue;            // uniform branch
    const int ci = cols[blk] * 64;
    const bf16_t* wblk = wpk + (size_t)blk * 65536;

    __syncthreads();   // all waves done reading xst/wlds from previous block

    // ---- stage x tile, transposed, f32 -> bf16 ----
    {
      const int i = tid >> 2, c = tid & 3;
      const float* xrow = x + ((size_t)n * C_LEN + (ci + i)) * T_LEN;
      if (c == 0) {                            // head: u = 0..14
        for (int u = 0; u < 15; ++u) {
          float v = (t0 == 0) ? 0.0f : xrow[t0 - 15 + u];
          xst[u * 72 + i] = (bf16_t)v;
        }
      }
      // body: u = 15 + 4f, f = c + 4q (interleaved -> ~4-way write conflicts)
      for (int q = 0; q < 32; ++q) {
        const int f = c + 4 * q;
        const float4 v = *(const float4*)(xrow + t0 + 4 * f);
        const int u = 15 + 4 * f;
        xst[(u + 0) * 72 + i] = (bf16_t)v.x;
        xst[(u + 1) * 72 + i] = (bf16_t)v.y;
        xst[(u + 2) * 72 + i] = (bf16_t)v.z;
        xst[(u + 3) * 72 + i] = (bf16_t)v.w;
      }
    }

    // ---- preload weight chunk 0 ----
    uint4 wreg[8];
    #pragma unroll
    for (int p = 0; p < 8; ++p)
      wreg[p] = *(const uint4*)(wblk + (size_t)(p * 256 + tid) * 8);
    #pragma unroll
    for (int p = 0; p < 8; ++p)
      *(uint4*)(&wlds[0][(p * 256 + tid) * 8]) = wreg[p];

    for (int chunk = 0; chunk < 4; ++chunk) {
      __syncthreads();   // xst staged + wlds[chunk&1] ready

      if (chunk < 3) {   // issue next chunk's global loads early (hidden)
        const bf16_t* wsrc = wblk + (size_t)(chunk + 1) * 16384;
        #pragma unroll
        for (int p = 0; p < 8; ++p)
          wreg[p] = *(const uint4*)(wsrc + (size_t)(p * 256 + tid) * 8);
      }

      const bf16_t* wl = wlds[chunk & 1];
      #pragma unroll
      for (int ksl = 0; ksl < 8; ++ksl) {
        const int ks = chunk * 8 + ksl;
        const int k  = ks >> 1;            // conv tap 0..15
        const int ih = (ks & 1) * 32;      // i half
        bf16x8 afr[4];
        #pragma unroll
        for (int mt = 0; mt < 4; ++mt)
          afr[mt] = *(const bf16x8*)(wl + ((ksl * 4 + mt) * 64 + lane) * 8);
        bf16x8 bfr[8];
        const int rb  = wv * 128 + (lane & 15) + k;
        const int col = ih + (lane >> 4) * 8;
        #pragma unroll
        for (int nt = 0; nt < 8; ++nt)
          bfr[nt] = *(const bf16x8*)(xst + (rb + nt * 16) * 72 + col);
        #pragma unroll
        for (int mt = 0; mt < 4; ++mt) {
          #pragma unroll
          for (int nt = 0; nt < 8; ++nt)
            acc[mt][nt] = __builtin_amdgcn_mfma_f32_16x16x32_bf16(
                afr[mt], bfr[nt], acc[mt][nt], 0, 0, 0);
        }
      }

      __syncthreads();
      if (chunk < 3) {
        bf16_t* wd = wlds[(chunk + 1) & 1];
        #pragma unroll
        for (int p = 0; p < 8; ++p)
          *(uint4*)(&wd[(p * 256 + tid) * 8]) = wreg[p];
      }
    }
  }

  // ---- store (each output element written exactly once, no atomics) ----
  const int mlo = (lane >> 4) * 4;
  const int nn  = lane & 15;
  #pragma unroll
  for (int mt = 0; mt < 4; ++mt) {
    #pragma unroll
    for (int nt = 0; nt < 8; ++nt) {
      const int t = t0 + wv * 128 + nt * 16 + nn;
      float* yp = y + ((size_t)n * C_LEN + (size_t)(tr * 64 + mt * 16 + mlo)) * T_LEN + t;
      #pragma unroll
      for (int r = 0; r < 4; ++r)
        yp[(size_t)r * T_LEN] = acc[mt][nt][r];
    }
  }
}

extern "C" void kernel_launch(void* const* d_in, const int* in_sizes, int n_in,
                              void* d_out, int out_size, void* d_ws, size_t ws_size,
                              hipStream_t stream) {
  const float* x   = (const float*)d_in[0];
  const float* bv  = (const float*)d_in[1];
  const int* cols  = (const int*)d_in[2];
  const int* rows  = (const int*)d_in[3];
  float* y = (float*)d_out;
  bf16_t* wpk = (bf16_t*)d_ws;   // 16.78 MB needed

  prepack_kernel<<<dim3(128, 4), dim3(256), 0, stream>>>(bv, wpk);
  bsconv_kernel<<<dim3(4, 32, 4), dim3(256), 0, stream>>>(x, wpk, cols, rows, y);
}

// Round 2
// 194.104 us; speedup vs baseline: 1.5787x; 1.5787x over previous
//
#include <hip/hip_runtime.h>
#include <hip/hip_bf16.h>
#include <stdint.h>

typedef __bf16 bf16_t;
typedef bf16_t bf16x8 __attribute__((ext_vector_type(8)));
typedef float f32x4 __attribute__((ext_vector_type(4)));

#define T_LEN 2048
#define C_LEN 2048
#define NB 128
#define TN 256
#define SROWS 2064   // 16 zero-halo rows + 2048 data rows per batch
#define XROWS 288    // LDS x rows staged (272 used; 288 = 9 full 4KB issues)

// async global->LDS, 16B per lane; LDS dest = wave-uniform base + lane*16
#define GLL(gp, lp) __builtin_amdgcn_global_load_lds( \
    (const __attribute__((address_space(1))) uint32_t*)(gp), \
    (__attribute__((address_space(3))) uint32_t*)(lp), 16, 0, 0)

// ---------------------------------------------------------------------------
// Prepack weights into per-lane MFMA A-fragment layout (unchanged, verified):
// wpk[blk][ks(32)][mt(4)][lane(64)][j(8)]
//   = bv[blk][o = mt*16 + (lane&15)][i = (ks&1)*32 + (lane>>4)*8 + j][k = ks>>1]
// ---------------------------------------------------------------------------
__global__ __launch_bounds__(256) void prepack_kernel(
    const float* __restrict__ bv, bf16_t* __restrict__ wpk)
{
  const int blk = blockIdx.x;
  const int mt  = blockIdx.y;
  const int tid = threadIdx.x;
  __shared__ float lw[16 * 64 * 17];

  const float* src = bv + (size_t)blk * 65536 + (size_t)mt * 16384;
  for (int p = 0; p < 16; ++p) {
    int idx = p * 1024 + tid * 4;
    const float4 v = *(const float4*)(src + idx);
    int o = idx >> 10;
    int i = (idx >> 4) & 63;
    int k = idx & 15;
    float* d = &lw[(o * 64 + i) * 17 + k];
    d[0] = v.x; d[1] = v.y; d[2] = v.z; d[3] = v.w;
  }
  __syncthreads();

  const int e0 = tid * 2;
  const int l  = e0 >> 3;
  const int j  = e0 & 7;
  const int o  = l & 15;
  for (int ks = 0; ks < 32; ++ks) {
    const int k  = ks >> 1;
    const int i0 = (ks & 1) * 32 + (l >> 4) * 8 + j;
    const float a = lw[(o * 64 + i0) * 17 + k];
    const float b = lw[(o * 64 + i0 + 1) * 17 + k];
    const uint16_t ba = __builtin_bit_cast(uint16_t, (bf16_t)a);
    const uint16_t bb = __builtin_bit_cast(uint16_t, (bf16_t)b);
    const uint32_t packed = (uint32_t)ba | ((uint32_t)bb << 16);
    const size_t off = ((((size_t)blk * 32 + ks) * 4 + mt) * 512) + e0;
    *(uint32_t*)(wpk + off) = packed;
  }
}

// ---------------------------------------------------------------------------
// Zero the halo rows of S: rows [n*SROWS, n*SROWS+16) per batch + 16 trailing.
// ---------------------------------------------------------------------------
__global__ __launch_bounds__(256) void padzero_kernel(bf16_t* __restrict__ S)
{
  const int p = blockIdx.x;  // 0..79
  const size_t g = (p < 64) ? ((size_t)(p >> 4) * SROWS + (p & 15))
                            : ((size_t)4 * SROWS + (p - 64));
  uint4 z = {0u, 0u, 0u, 0u};
  *(uint4*)(S + g * C_LEN + (size_t)threadIdx.x * 8) = z;
}

// ---------------------------------------------------------------------------
// x prepass: f32 [n][c][t] -> bf16 S[n][16+t][c'] where within each 64-ch
// block, c' = c ^ ((t&7)<<3)  (st-style XOR swizzle baked into global layout
// so the main kernel's linear global_load_lds yields swizzled LDS).
// ---------------------------------------------------------------------------
__global__ __launch_bounds__(256) void xprep_kernel(
    const float* __restrict__ x, bf16_t* __restrict__ S)
{
  const int tb = blockIdx.x, cb = blockIdx.y, n = blockIdx.z;
  const int tid = threadIdx.x;
  __shared__ float lt[64 * 67 + 4];   // [c][t_], stride 67 -> 2-way max on reads

  #pragma unroll
  for (int p = 0; p < 4; ++p) {
    const int idx = p * 256 + tid;      // 0..1023
    const int c   = idx >> 4;           // 0..63
    const int t4  = (idx & 15) * 4;
    const float4 v = *(const float4*)(
        x + ((size_t)n * C_LEN + cb * 64 + c) * T_LEN + tb * 64 + t4);
    float* d = &lt[c * 67 + t4];
    d[0] = v.x; d[1] = v.y; d[2] = v.z; d[3] = v.w;
  }
  __syncthreads();

  #pragma unroll
  for (int p = 0; p < 2; ++p) {
    const int idx = p * 256 + tid;      // 0..511
    const int tl  = idx >> 3;           // 0..63
    const int seg = idx & 7;
    const int t   = tb * 64 + tl;
    const int cbase = (seg * 8) ^ ((t & 7) << 3);
    uint32_t w[4];
    #pragma unroll
    for (int h = 0; h < 4; ++h) {
      const float a = lt[(cbase + 2 * h) * 67 + tl];
      const float b = lt[(cbase + 2 * h + 1) * 67 + tl];
      const uint16_t ba = __builtin_bit_cast(uint16_t, (bf16_t)a);
      const uint16_t bb = __builtin_bit_cast(uint16_t, (bf16_t)b);
      w[h] = (uint32_t)ba | ((uint32_t)bb << 16);
    }
    uint4 u4 = {w[0], w[1], w[2], w[3]};
    *(uint4*)(S + ((size_t)n * SROWS + 16 + t) * C_LEN + cb * 64 + seg * 8) = u4;
  }
}

// ---------------------------------------------------------------------------
// Main kernel. WG = (t-tile of 256, target row, batch). All staging via
// global_load_lds; W double-buffered in 16KB chunks; counted vmcnt(4) +
// raw barriers (T3+T4). acc in regs; one store per output element.
// Per-wave vmcnt ledger: [x:9][W0:4] | loop c: issue Wc+1:4, wait vmcnt(4)
// (=> x + chunks<=c landed), barrier, compute c, barrier.  Buf (c+1)&1 was
// last read in compute c-1, which finished at the trailing barrier of c-1,
// strictly before the c-th issue. rows/cols read from LDS (no vmcnt noise).
// ---------------------------------------------------------------------------
__global__ __launch_bounds__(256, 2) void bsconv_kernel(
    const bf16_t* __restrict__ S, const bf16_t* __restrict__ wpk,
    const int* __restrict__ cols, const int* __restrict__ rows,
    float* __restrict__ y)
{
  const int tt = blockIdx.x, tr = blockIdx.y, n = blockIdx.z;
  const int t0 = tt * TN;
  const int tid = threadIdx.x;
  const int lane = tid & 63, wv = tid >> 6;

  __shared__ __attribute__((aligned(16))) bf16_t xst[XROWS * 64];   // 36864 B
  __shared__ __attribute__((aligned(16))) bf16_t wlds[2][8192];     // 32768 B
  __shared__ int rlds[NB], clds[NB];

  if (tid < NB) rlds[tid] = rows[tid];
  else          clds[tid - NB] = cols[tid - NB];
  __syncthreads();   // drains all vmem: vmcnt ledger starts at 0

  f32x4 acc[4][4];
  #pragma unroll
  for (int a = 0; a < 4; ++a)
    #pragma unroll
    for (int b = 0; b < 4; ++b) {
      f32x4 z = {0.f, 0.f, 0.f, 0.f};
      acc[a][b] = z;
    }

  const size_t srow0 = (size_t)n * SROWS + t0;  // S row of LDS row u=0 (t=t0-16)
  const int lxb = wv * 1024 + lane * 16;        // lane byte within a 4KB issue

  for (int blk = 0; blk < NB; ++blk) {
    if (rlds[blk] != tr) continue;              // uniform at runtime
    const int cb = clds[blk];
    const bf16_t* wblk = wpk + (size_t)blk * 65536;

    // ---- issue x staging: 9 x 4KB -> xst (linear; swizzle pre-baked in S)
    #pragma unroll
    for (int q = 0; q < 9; ++q) {
      const int lb = q * 4096 + lxb;
      const int u  = lb >> 7;             // LDS row (128 B rows)
      const int ib = (lb >> 1) & 63;      // element within row
      const bf16_t* gp = S + (srow0 + u) * C_LEN + cb * 64 + ib;
      GLL(gp, (char*)xst + lb);
    }
    // ---- issue W chunk 0 (ks 0..3, 16KB)
    #pragma unroll
    for (int p = 0; p < 4; ++p) {
      const int lb = p * 4096 + lxb;
      GLL(wblk + (lb >> 1), (char*)wlds[0] + lb);
    }

    for (int ch = 0; ch < 8; ++ch) {
      if (ch < 7) {
        bf16_t* wd = wlds[(ch + 1) & 1];
        const bf16_t* gsrc = wblk + (size_t)(ch + 1) * 8192;
        #pragma unroll
        for (int p = 0; p < 4; ++p) {
          const int lb = p * 4096 + lxb;
          GLL(gsrc + (lb >> 1), (char*)wd + lb);
        }
        asm volatile("s_waitcnt vmcnt(4)" ::: "memory");  // x + chunks<=ch done
      } else {
        asm volatile("s_waitcnt vmcnt(0)" ::: "memory");
      }
      __builtin_amdgcn_s_barrier();           // B_ready(ch)
      __builtin_amdgcn_sched_barrier(0);

      const bf16_t* wl = wlds[ch & 1];
      #pragma unroll
      for (int ksl = 0; ksl < 4; ++ksl) {
        const int ks = ch * 4 + ksl;
        const int k  = ks >> 1;               // conv tap
        const int ih = (ks & 1) * 32;         // channel half
        bf16x8 afr[4];
        #pragma unroll
        for (int mt = 0; mt < 4; ++mt)
          afr[mt] = *(const bf16x8*)(wl + ((ksl * 4 + mt) * 64 + lane) * 8);
        const int ub = wv * 64 + (lane & 15) + k + 1;       // LDS row base
        const int scol = (ih + ((lane >> 4) & 3) * 8) ^ ((ub & 7) << 3);
        bf16x8 bfr[4];
        #pragma unroll
        for (int nt = 0; nt < 4; ++nt)
          bfr[nt] = *(const bf16x8*)(xst + (ub + nt * 16) * 64 + scol);
        #pragma unroll
        for (int mt = 0; mt < 4; ++mt)
          #pragma unroll
          for (int nt = 0; nt < 4; ++nt)
            acc[mt][nt] = __builtin_amdgcn_mfma_f32_16x16x32_bf16(
                afr[mt], bfr[nt], acc[mt][nt], 0, 0, 0);
      }
      __builtin_amdgcn_sched_barrier(0);
      __builtin_amdgcn_s_barrier();           // B_done(ch): bufs reusable
    }
  }

  // ---- store (each output element exactly once; zero rows store zeros)
  const int mlo = ((lane >> 4) & 3) * 4, nn = lane & 15;
  #pragma unroll
  for (int mt = 0; mt < 4; ++mt) {
    #pragma unroll
    for (int nt = 0; nt < 4; ++nt) {
      const int t = t0 + wv * 64 + nt * 16 + nn;
      float* yp = y + ((size_t)n * C_LEN + (size_t)(tr * 64 + mt * 16 + mlo)) * T_LEN + t;
      #pragma unroll
      for (int r = 0; r < 4; ++r)
        yp[(size_t)r * T_LEN] = acc[mt][nt][r];
    }
  }
}

extern "C" void kernel_launch(void* const* d_in, const int* in_sizes, int n_in,
                              void* d_out, int out_size, void* d_ws, size_t ws_size,
                              hipStream_t stream) {
  const float* x   = (const float*)d_in[0];
  const float* bv  = (const float*)d_in[1];
  const int* cols  = (const int*)d_in[2];
  const int* rows  = (const int*)d_in[3];
  float* y = (float*)d_out;

  // ws layout: [wpk: 16,777,216 B][S: 33,882,112 B]  (needs ws >= 50.7 MB)
  bf16_t* wpk = (bf16_t*)d_ws;
  bf16_t* S   = (bf16_t*)((char*)d_ws + 16777216);

  prepack_kernel<<<dim3(128, 4), dim3(256), 0, stream>>>(bv, wpk);
  padzero_kernel<<<dim3(80), dim3(256), 0, stream>>>(S);
  xprep_kernel<<<dim3(32, 32, 4), dim3(256), 0, stream>>>(x, S);
  bsconv_kernel<<<dim3(8, 32, 4), dim3(256), 0, stream>>>(S, wpk, cols, rows, y);
}